// Round 5
// baseline (1361.719 us; speedup 1.0000x reference)
//
#include <hip/hip_runtime.h>
#include <hip/hip_fp16.h>
#include <stdint.h>

#define D_IN   768
#define D_SAE  12288
#define BATCH  8192
#define K_TOP  64
#define CAND_MAX 256

typedef _Float16 f16;
typedef _Float16 v8h __attribute__((ext_vector_type(8)));
typedef float v4f __attribute__((ext_vector_type(4)));

// async global->LDS, 16B/lane, wave-uniform LDS base (lane writes base + lane*16B)
__device__ inline void async16(const void* g, void* l) {
    __builtin_amdgcn_global_load_lds(
        (const __attribute__((address_space(1))) unsigned int*)g,
        (__attribute__((address_space(3))) unsigned int*)l, 16, 0, 0);
}

// ---------------- convert x: (x - b_dec) -> f16 hi plane [BATCH][D_IN] ----------------
__global__ __launch_bounds__(256) void k_convert_x(
    const float* __restrict__ x, const float* __restrict__ b_dec,
    f16* __restrict__ xhi)
{
    int i4 = (blockIdx.x * 256 + threadIdx.x) * 4;
    float4 v = *(const float4*)(x + i4);
    int col = i4 % D_IN;
    float vv[4] = { v.x - b_dec[col], v.y - b_dec[col + 1],
                    v.z - b_dec[col + 2], v.w - b_dec[col + 3] };
    union { short4 s; f16 h[4]; } H;
#pragma unroll
    for (int u = 0; u < 4; ++u) H.h[u] = (f16)vv[u];
    *(short4*)(xhi + i4) = H.s;
}

// ---------------- convert+transpose W_enc [D_IN][D_SAE] -> hi/lo planes [D_SAE][D_IN] ----------------
__global__ __launch_bounds__(256) void k_convert_wt(
    const float* __restrict__ W, f16* __restrict__ whiT, f16* __restrict__ wloT)
{
    __shared__ float tile[32][33];
    const int n0 = blockIdx.x * 32;
    const int k0 = blockIdx.y * 32;
    const int c = threadIdx.x & 31;
    const int rr = threadIdx.x >> 5;   // 0..7
#pragma unroll
    for (int s = 0; s < 4; ++s) {
        int r = s * 8 + rr;
        tile[r][c] = W[(size_t)(k0 + r) * D_SAE + n0 + c];
    }
    __syncthreads();
#pragma unroll
    for (int s = 0; s < 4; ++s) {
        int r2 = s * 8 + rr;                 // n within tile
        float v = tile[c][r2];               // W[k0+c][n0+r2]
        f16 hi = (f16)v;
        f16 lo = (f16)(v - (float)hi);
        whiT[(size_t)(n0 + r2) * D_IN + k0 + c] = hi;
        wloT[(size_t)(n0 + r2) * D_IN + k0 + c] = lo;
    }
}

// ---------------- convert W_dec [D_SAE][D_IN] fp32 -> f16 (decode is tolerant:
// per-term err <= val*|w|*2^-12, RMS over 64 terms ~2e-4 on recon) ----------------
__global__ __launch_bounds__(256) void k_convert_wd(
    const float* __restrict__ W, f16* __restrict__ Wh)
{
    int i4 = (blockIdx.x * 256 + threadIdx.x) * 4;
    float4 v = *(const float4*)(W + i4);
    union { short4 s; f16 h[4]; } H;
    H.h[0] = (f16)v.x; H.h[1] = (f16)v.y; H.h[2] = (f16)v.z; H.h[3] = (f16)v.w;
    *(short4*)(Wh + i4) = H.s;
}

// ---------------- approximate encode GEMM (f16 MFMA, 128x128 tile, BK=64) ----------------
// Round-0 proven structure. Writes relu(A*Bt^T + b_enc) rounded to f16 (nontemporal)
// into the FIRST 24 KB of each row's fp32 span. NEW: epilogue also zeroes this
// block's column-slice of the row's SECOND 24 KB (fp32 [6144,12288)), so k_topk2
// only needs to zero-fill the first half. Epilogue has no barriers after it, so
// these stores drain in the store shadow (no vmcnt-stall mechanism).
__global__ __launch_bounds__(256) void k_gemm_f16(
    const f16* __restrict__ A,    // Xhi [BATCH][D_IN]
    const f16* __restrict__ Bt,   // WhiT [D_SAE][D_IN]
    const float* __restrict__ b_enc,
    f16* __restrict__ outap)      // rows of 2*D_SAE f16 (= D_SAE fp32)
{
    __shared__ f16 Asm[2][128 * 32];
    __shared__ f16 Bsm[2][128 * 32];
    const int tid  = threadIdx.x;
    const int wave = tid >> 6;
    const int lane = tid & 63;
    const int bn = blockIdx.x * 128;
    const int bm = blockIdx.y * 128;

    const int r16  = lane >> 2;       // 0..15 staging row
    const int kc8  = (lane & 3) * 8;  // f16 k-offset within 32
    const int mrow = lane & 15;
    const int quad = lane >> 4;
    const int wm = (wave & 1) * 64;
    const int wn = (wave >> 1) * 64;

    v4f acc[4][4] = {};

    const f16* gA = A  + (size_t)(bm + wave * 32 + r16) * D_IN + kc8;
    const f16* gB = Bt + (size_t)(bn + wave * 32 + r16) * D_IN + kc8;
    f16* lA0  = &Asm[0][(wave * 32) * 32];
    f16* lA0b = &Asm[0][(wave * 32 + 16) * 32];
    f16* lB0  = &Bsm[0][(wave * 32) * 32];
    f16* lB0b = &Bsm[0][(wave * 32 + 16) * 32];
    f16* lA1  = &Asm[1][(wave * 32) * 32];
    f16* lA1b = &Asm[1][(wave * 32 + 16) * 32];
    f16* lB1  = &Bsm[1][(wave * 32) * 32];
    f16* lB1b = &Bsm[1][(wave * 32 + 16) * 32];

    for (int k0 = 0; k0 < D_IN; k0 += 64) {
        __syncthreads();
        async16(gA + k0,               lA0);
        async16(gA + k0 + 16 * D_IN,   lA0b);
        async16(gB + k0,               lB0);
        async16(gB + k0 + 16 * D_IN,   lB0b);
        async16(gA + k0 + 32,              lA1);
        async16(gA + k0 + 32 + 16 * D_IN,  lA1b);
        async16(gB + k0 + 32,              lB1);
        async16(gB + k0 + 32 + 16 * D_IN,  lB1b);
        __syncthreads();

#pragma unroll
        for (int s = 0; s < 2; ++s) {
            v8h af[4], bf[4];
#pragma unroll
            for (int i = 0; i < 4; ++i)
                af[i] = *(const v8h*)&Asm[s][(wm + i * 16 + mrow) * 32 + quad * 8];
#pragma unroll
            for (int j = 0; j < 4; ++j)
                bf[j] = *(const v8h*)&Bsm[s][(wn + j * 16 + mrow) * 32 + quad * 8];
#pragma unroll
            for (int i = 0; i < 4; ++i)
#pragma unroll
                for (int j = 0; j < 4; ++j)
                    acc[i][j] = __builtin_amdgcn_mfma_f32_16x16x32_f16(af[i], bf[j], acc[i][j], 0, 0, 0);
        }
    }

#pragma unroll
    for (int i = 0; i < 4; ++i) {
#pragma unroll
        for (int r = 0; r < 4; ++r) {
            int grow = bm + wm + i * 16 + quad * 4 + r;
            f16* op = outap + (size_t)grow * (2 * D_SAE) + bn + wn;
#pragma unroll
            for (int j = 0; j < 4; ++j) {
                int c = j * 16 + mrow;
                float val = acc[i][j][r] + b_enc[bn + wn + c];
                __builtin_nontemporal_store((f16)(val > 0.f ? val : 0.f), op + c);
            }
        }
    }

    // ---- zero this block's slice of the rows' second half: fp32 range
    // [D_SAE/2 + bx*64, +64) for rows [bm, bm+128). 32 KB/block, no barriers after.
    {
        float* zbase = (float*)outap;                 // row stride D_SAE fp32
        const int r = tid >> 1;                       // 0..127
        const int half = (tid & 1) * 32;              // 0 or 32 floats
        float* zp = zbase + (size_t)(bm + r) * D_SAE + (D_SAE / 2)
                  + blockIdx.x * 64 + half;
        v4f z = {0.f, 0.f, 0.f, 0.f};
#pragma unroll
        for (int q = 0; q < 8; ++q)
            __builtin_nontemporal_store(z, (v4f*)(zp + q * 4));
    }
}

// 256-bin suffix scan via wave shfl + 4-wave LDS combine.
__device__ __forceinline__ unsigned suffix_scan_256(unsigned h, int t, unsigned* wtot, unsigned* tot_out) {
    const int lane = t & 63;
    const int w = t >> 6;
    unsigned s = h;
#pragma unroll
    for (int off = 1; off < 64; off <<= 1) {
        unsigned o = __shfl_down(s, off);
        if (lane + off < 64) s += o;
    }
    if (lane == 0) wtot[w] = s;
    __syncthreads();
    unsigned suf = s;
    unsigned tot = 0;
#pragma unroll
    for (int w2 = 0; w2 < 4; ++w2) {
        tot += wtot[w2];
        if (w2 > w) suf += wtot[w2];
    }
    *tot_out = tot;
    return suf;
}

// ---------------- per-row: cutoff/compaction + sequential exact recompute + scatter + decode ----------------
__global__ __launch_bounds__(256) void k_topk2(
    float* __restrict__ sparse,        // [BATCH][D_SAE]: in f16 approx (first half), out final sparse_acts
    const float* __restrict__ x,       // original fp32 [BATCH][D_IN]
    const f16* __restrict__ WhiT, const f16* __restrict__ WloT,
    const float* __restrict__ b_enc,
    const f16* __restrict__ Wdh,       // f16 W_dec [D_SAE][D_IN]
    const float* __restrict__ b_dec,
    float* __restrict__ recon)         // [BATCH][D_IN]
{
    const int row = blockIdx.x;
    const int t = threadIdx.x;
    const int lane = t & 63;
    float* rp = sparse + (size_t)row * D_SAE;
    const f16* ap = (const f16*)rp;

    // ---- load f16 approx row, 48 per thread, coalesced 16B, nontemporal ----
    v8h av[6];
#pragma unroll
    for (int j = 0; j < 6; ++j)
        av[j] = __builtin_nontemporal_load((const v8h*)(ap + ((size_t)j * 256 + t) * 8));

    __shared__ unsigned hist[256];
    __shared__ unsigned wtot[4];
    __shared__ float sh_cutoff;
    __shared__ int sh_ncand;
    __shared__ int   cand_i[CAND_MAX];
    __shared__ float cand_v[CAND_MAX];
    __shared__ float kept_v[K_TOP];
    __shared__ int   kept_i[K_TOP];
    __shared__ float xr[D_IN];

    const float margin = 0.05f;

    hist[t] = 0;
    if (t == 0) sh_ncand = 0;
    // overlap: exact x row (fp32, centered) into LDS for the recompute phase
    for (int k = t; k < D_IN; k += 256)
        xr[k] = x[(size_t)row * D_IN + k] - b_dec[k];
    __syncthreads();

    // ---- level 0: histogram over [2.0, 10.0), 1/32 bins. Top-64/12288 cutoff sits
    // near 3.6 for this problem's statistics; only ~8% of elements take the atomic.
    // Pathological rows fall back to the proven [0.25,8.25) / (0,0.25) ladder. ----
#pragma unroll
    for (int j = 0; j < 6; ++j)
#pragma unroll
        for (int u = 0; u < 8; ++u) {
            float x0 = (float)av[j][u];
            if (x0 >= 2.0f) {
                int b = (int)((x0 - 2.0f) * 32.0f); if (b > 255) b = 255;
                atomicAdd(&hist[b], 1u);
            }
        }
    __syncthreads();
    unsigned h0 = hist[t];
    unsigned tot0;
    unsigned suf0 = suffix_scan_256(h0, t, wtot, &tot0);
    if (tot0 >= K_TOP) {
        if (suf0 >= K_TOP && suf0 - h0 < K_TOP)
            sh_cutoff = fmaxf(2.0f + (float)t * (1.0f / 32.0f) - margin, 1e-30f);
    }
    __syncthreads();
    if (tot0 < K_TOP) {
        // ---- level 1: [0.25, 8.25), 1/32 bins (original proven range) ----
        hist[t] = 0;
        __syncthreads();
#pragma unroll
        for (int j = 0; j < 6; ++j)
#pragma unroll
            for (int u = 0; u < 8; ++u) {
                float x0 = (float)av[j][u];
                if (x0 >= 0.25f) {
                    int b = (int)(x0 * 32.0f); if (b > 255) b = 255;
                    atomicAdd(&hist[b], 1u);
                }
            }
        __syncthreads();
        unsigned h1 = hist[t];
        unsigned tot1;
        unsigned suf1 = suffix_scan_256(h1, t, wtot, &tot1);
        if (tot1 >= K_TOP) {
            if (suf1 >= K_TOP && suf1 - h1 < K_TOP)
                sh_cutoff = fmaxf((float)t * (1.0f / 32.0f) - margin, 1e-30f);
        }
        __syncthreads();
        if (tot1 < K_TOP) {
            // ---- level 2: refine (0, 0.25) ----
            hist[t] = 0;
            __syncthreads();
#pragma unroll
            for (int j = 0; j < 6; ++j)
#pragma unroll
                for (int u = 0; u < 8; ++u) {
                    float x0 = (float)av[j][u];
                    if (x0 > 0.0f && x0 < 0.25f) {
                        int b = (int)(x0 * 1024.0f); if (b > 255) b = 255;
                        atomicAdd(&hist[b], 1u);
                    }
                }
            __syncthreads();
            unsigned h2 = hist[t];
            unsigned tot2;
            unsigned suf2 = suffix_scan_256(h2, t, wtot, &tot2);
            unsigned need = K_TOP - tot1;
            if (tot2 >= need) {
                if (suf2 >= need && suf2 - h2 < need)
                    sh_cutoff = fmaxf((float)t * (1.0f / 1024.0f) - margin, 1e-30f);
            } else {
                if (t == 0) sh_cutoff = 1e-30f;  // fewer than K positives: keep all positives
            }
        }
    }
    __syncthreads();
    const float cutoff = sh_cutoff;

    // ---- collect candidate indices: ballot + prefix-popcount ----
#pragma unroll
    for (int j = 0; j < 6; ++j)
#pragma unroll
        for (int u = 0; u < 8; ++u) {
            float x0 = (float)av[j][u];
            bool pass = (x0 >= cutoff);
            unsigned long long m = __ballot(pass);
            if (m != 0ull) {
                int leader = (int)__builtin_ctzll(m);
                int cnt = (int)__builtin_popcountll(m);
                int base0 = 0;
                if (lane == leader) base0 = atomicAdd(&sh_ncand, cnt);
                base0 = __shfl(base0, leader);
                if (pass) {
                    int pos = base0 + (int)__builtin_popcountll(m & ((1ull << lane) - 1ull));
                    if (pos < CAND_MAX) { cand_i[pos] = (j * 256 + t) * 8 + u; cand_v[pos] = x0; }
                }
            }
        }
    __syncthreads();
    int ncand = sh_ncand; if (ncand > CAND_MAX) ncand = CAND_MAX;

    // ---- exact recompute: SEQUENTIAL k per thread — rounding correlated with
    //      the np reference; DO NOT parallelize or reorder this sum ----
    for (int c = t; c < ncand; c += 256) {
        const f16* wh = WhiT + (size_t)cand_i[c] * D_IN;
        const f16* wl = WloT + (size_t)cand_i[c] * D_IN;
        float acc = 0.f;
        for (int k = 0; k < D_IN; k += 8) {
            v8h hv = *(const v8h*)(wh + k);
            v8h lv = *(const v8h*)(wl + k);
#pragma unroll
            for (int u = 0; u < 8; ++u)
                acc += xr[k + u] * ((float)hv[u] + (float)lv[u]);
        }
        acc += b_enc[cand_i[c]];
        cand_v[c] = acc > 0.f ? acc : 0.f;
    }
    __syncthreads();

    // ---- exact ranking (value desc, index asc), rank-indexed kept store ----
    for (int c = t; c < ncand; c += 256) {
        float vc = cand_v[c]; int ic = cand_i[c];
        int r = 0;
        for (int m = 0; m < ncand; ++m) {
            float vm = cand_v[m];
            r += (vm > vc || (vm == vc && cand_i[m] < ic)) ? 1 : 0;
        }
        if (r < K_TOP) { kept_v[r] = vc; kept_i[r] = ic; }
    }
    __syncthreads();
    int nk = ncand < K_TOP ? ncand : K_TOP;

    // ---- zero-fill FIRST HALF only (second half was zeroed by the GEMM epilogue),
    //      then scatter exact values over the full row ----
#pragma unroll
    for (int j = 0; j < 6; ++j) {
        v4f z = {0.f, 0.f, 0.f, 0.f};
        __builtin_nontemporal_store(z, (v4f*)(rp + ((size_t)j * 256 + t) * 4));
    }
    __syncthreads();
    if (t < nk) rp[kept_i[t]] = kept_v[t];

    // ---- sparse decode (f16 W_dec): recon = sum kept_v * Wdh[kept_i,:] + b_dec ----
    float r0 = b_dec[t], r1 = b_dec[t + 256], r2 = b_dec[t + 512];
#pragma unroll 4
    for (int m = 0; m < nk; ++m) {
        float val = kept_v[m];
        const f16* wr = Wdh + (size_t)kept_i[m] * D_IN;
        r0 += val * (float)wr[t];
        r1 += val * (float)wr[t + 256];
        r2 += val * (float)wr[t + 512];
    }
    float* rc = recon + (size_t)row * D_IN;
    __builtin_nontemporal_store(r0, rc + t);
    __builtin_nontemporal_store(r1, rc + t + 256);
    __builtin_nontemporal_store(r2, rc + t + 512);
}

extern "C" void kernel_launch(void* const* d_in, const int* in_sizes, int n_in,
                              void* d_out, int out_size, void* d_ws, size_t ws_size,
                              hipStream_t stream) {
    const float* x     = (const float*)d_in[0];
    const float* W_enc = (const float*)d_in[1];
    const float* b_enc = (const float*)d_in[2];
    const float* W_dec = (const float*)d_in[3];
    const float* b_dec = (const float*)d_in[4];
    float* out    = (float*)d_out;
    float* recon  = out;                             // [BATCH][D_IN]
    float* sparse = out + (size_t)BATCH * D_IN;      // [BATCH][D_SAE]

    const size_t xplane = (size_t)BATCH * D_IN;      // 6291456
    const size_t wplane = (size_t)D_SAE * D_IN;      // 9437184
    // workspace layout identical to the last PASSING round (69.2 MB)
    f16* xhi    = (f16*)d_ws;                        // 12.6 MB
    f16* whiT   = xhi + xplane;                      // 18.9 MB
    f16* wloT   = whiT + wplane;                     // 18.9 MB
    f16* wdh    = wloT + wplane;                     // 18.9 MB

    k_convert_x<<<xplane / 1024, 256, 0, stream>>>(x, b_dec, xhi);
    k_convert_wt<<<dim3(D_SAE / 32, D_IN / 32), 256, 0, stream>>>(W_enc, whiT, wloT);
    k_convert_wd<<<wplane / 1024, 256, 0, stream>>>(W_dec, wdh);
    k_gemm_f16<<<dim3(D_SAE / 128, BATCH / 128), 256, 0, stream>>>(xhi, whiT, b_enc, (f16*)sparse);
    k_topk2<<<BATCH, 256, 0, stream>>>(sparse, x, whiT, wloT, b_enc, wdh, b_dec, recon);
}

// Round 6
// 1196.754 us; speedup vs baseline: 1.1378x; 1.1378x over previous
//
#include <hip/hip_runtime.h>
#include <hip/hip_fp16.h>
#include <stdint.h>

#define D_IN   768
#define D_SAE  12288
#define BATCH  8192
#define K_TOP  64
#define CAND_MAX 256

typedef _Float16 f16;
typedef _Float16 v8h __attribute__((ext_vector_type(8)));
typedef float v4f __attribute__((ext_vector_type(4)));

// async global->LDS, 16B/lane, wave-uniform LDS base (lane writes base + lane*16B)
__device__ inline void async16(const void* g, void* l) {
    __builtin_amdgcn_global_load_lds(
        (const __attribute__((address_space(1))) unsigned int*)g,
        (__attribute__((address_space(3))) unsigned int*)l, 16, 0, 0);
}

// ---------------- convert x: (x - b_dec) -> f16 hi plane [BATCH][D_IN] ----------------
__global__ __launch_bounds__(256) void k_convert_x(
    const float* __restrict__ x, const float* __restrict__ b_dec,
    f16* __restrict__ xhi)
{
    int i4 = (blockIdx.x * 256 + threadIdx.x) * 4;
    float4 v = *(const float4*)(x + i4);
    int col = i4 % D_IN;
    float vv[4] = { v.x - b_dec[col], v.y - b_dec[col + 1],
                    v.z - b_dec[col + 2], v.w - b_dec[col + 3] };
    union { short4 s; f16 h[4]; } H;
#pragma unroll
    for (int u = 0; u < 4; ++u) H.h[u] = (f16)vv[u];
    *(short4*)(xhi + i4) = H.s;
}

// ---------------- convert+transpose W_enc [D_IN][D_SAE] -> hi/lo planes [D_SAE][D_IN] ----------------
__global__ __launch_bounds__(256) void k_convert_wt(
    const float* __restrict__ W, f16* __restrict__ whiT, f16* __restrict__ wloT)
{
    __shared__ float tile[32][33];
    const int n0 = blockIdx.x * 32;
    const int k0 = blockIdx.y * 32;
    const int c = threadIdx.x & 31;
    const int rr = threadIdx.x >> 5;   // 0..7
#pragma unroll
    for (int s = 0; s < 4; ++s) {
        int r = s * 8 + rr;
        tile[r][c] = W[(size_t)(k0 + r) * D_SAE + n0 + c];
    }
    __syncthreads();
#pragma unroll
    for (int s = 0; s < 4; ++s) {
        int r2 = s * 8 + rr;                 // n within tile
        float v = tile[c][r2];               // W[k0+c][n0+r2]
        f16 hi = (f16)v;
        f16 lo = (f16)(v - (float)hi);
        whiT[(size_t)(n0 + r2) * D_IN + k0 + c] = hi;
        wloT[(size_t)(n0 + r2) * D_IN + k0 + c] = lo;
    }
}

// ---------------- convert W_dec [D_SAE][D_IN] fp32 -> f16 (decode is tolerant:
// per-term err <= val*|w|*2^-12, RMS over 64 terms ~2e-4 on recon) ----------------
__global__ __launch_bounds__(256) void k_convert_wd(
    const float* __restrict__ W, f16* __restrict__ Wh)
{
    int i4 = (blockIdx.x * 256 + threadIdx.x) * 4;
    float4 v = *(const float4*)(W + i4);
    union { short4 s; f16 h[4]; } H;
    H.h[0] = (f16)v.x; H.h[1] = (f16)v.y; H.h[2] = (f16)v.z; H.h[3] = (f16)v.w;
    *(short4*)(Wh + i4) = H.s;
}

// ---------------- approximate encode GEMM (f16 MFMA, 128x128 tile, BK=64) ----------------
// Round-0 proven main loop. NEW epilogue: stage bias+ReLU'd f16 C-tile through LDS
// (union'd with the A/B staging buffers, stride 136 to rotate banks) and store
// 16 B/lane nontemporal — waves emit 256 B contiguous row-segments instead of the
// previous scalar 2 B stores (four disjoint 32 B fragments per instruction).
// Round-5 lesson: scattered small stores run ~5x slower than contiguous.
__global__ __launch_bounds__(256) void k_gemm_f16(
    const f16* __restrict__ A,    // Xhi [BATCH][D_IN]
    const f16* __restrict__ Bt,   // WhiT [D_SAE][D_IN]
    const float* __restrict__ b_enc,
    f16* __restrict__ outap)      // rows of 2*D_SAE f16 (= D_SAE fp32): approx in first half
{
    __shared__ union {
        struct { f16 A[2][128 * 32]; f16 B[2][128 * 32]; } ab;   // 32 KB
        f16 C[128 * 136];                                        // 34 KB
    } sm;
    const int tid  = threadIdx.x;
    const int wave = tid >> 6;
    const int lane = tid & 63;
    const int bn = blockIdx.x * 128;
    const int bm = blockIdx.y * 128;

    const int r16  = lane >> 2;       // 0..15 staging row
    const int kc8  = (lane & 3) * 8;  // f16 k-offset within 32
    const int mrow = lane & 15;
    const int quad = lane >> 4;
    const int wm = (wave & 1) * 64;
    const int wn = (wave >> 1) * 64;

    v4f acc[4][4] = {};

    const f16* gA = A  + (size_t)(bm + wave * 32 + r16) * D_IN + kc8;
    const f16* gB = Bt + (size_t)(bn + wave * 32 + r16) * D_IN + kc8;
    f16* lA0  = &sm.ab.A[0][(wave * 32) * 32];
    f16* lA0b = &sm.ab.A[0][(wave * 32 + 16) * 32];
    f16* lB0  = &sm.ab.B[0][(wave * 32) * 32];
    f16* lB0b = &sm.ab.B[0][(wave * 32 + 16) * 32];
    f16* lA1  = &sm.ab.A[1][(wave * 32) * 32];
    f16* lA1b = &sm.ab.A[1][(wave * 32 + 16) * 32];
    f16* lB1  = &sm.ab.B[1][(wave * 32) * 32];
    f16* lB1b = &sm.ab.B[1][(wave * 32 + 16) * 32];

    for (int k0 = 0; k0 < D_IN; k0 += 64) {
        __syncthreads();
        async16(gA + k0,               lA0);
        async16(gA + k0 + 16 * D_IN,   lA0b);
        async16(gB + k0,               lB0);
        async16(gB + k0 + 16 * D_IN,   lB0b);
        async16(gA + k0 + 32,              lA1);
        async16(gA + k0 + 32 + 16 * D_IN,  lA1b);
        async16(gB + k0 + 32,              lB1);
        async16(gB + k0 + 32 + 16 * D_IN,  lB1b);
        __syncthreads();

#pragma unroll
        for (int s = 0; s < 2; ++s) {
            v8h af[4], bf[4];
#pragma unroll
            for (int i = 0; i < 4; ++i)
                af[i] = *(const v8h*)&sm.ab.A[s][(wm + i * 16 + mrow) * 32 + quad * 8];
#pragma unroll
            for (int j = 0; j < 4; ++j)
                bf[j] = *(const v8h*)&sm.ab.B[s][(wn + j * 16 + mrow) * 32 + quad * 8];
#pragma unroll
            for (int i = 0; i < 4; ++i)
#pragma unroll
                for (int j = 0; j < 4; ++j)
                    acc[i][j] = __builtin_amdgcn_mfma_f32_16x16x32_f16(af[i], bf[j], acc[i][j], 0, 0, 0);
        }
    }

    // ---- epilogue: C tile -> LDS (values identical to before: +bias, relu, f16 round) ----
    __syncthreads();   // all waves done reading A/B staging LDS
#pragma unroll
    for (int i = 0; i < 4; ++i)
#pragma unroll
        for (int j = 0; j < 4; ++j)
#pragma unroll
            for (int r = 0; r < 4; ++r) {
                int lrow = wm + i * 16 + quad * 4 + r;
                int lcol = wn + j * 16 + mrow;
                float val = acc[i][j][r] + b_enc[bn + lcol];
                sm.C[lrow * 136 + lcol] = (f16)(val > 0.f ? val : 0.f);
            }
    __syncthreads();
    // ---- coalesced store: 8 rows/thread, 16 B each; wave = 4x 256 B contiguous segments ----
    {
        const int r0 = tid >> 4;          // 0..15
        const int c8 = (tid & 15) * 8;    // 0..120
#pragma unroll
        for (int q = 0; q < 8; ++q) {
            int lrow = r0 + q * 16;
            v8h v = *(const v8h*)&sm.C[lrow * 136 + c8];
            __builtin_nontemporal_store(v,
                (v8h*)(outap + (size_t)(bm + lrow) * (2 * D_SAE) + bn + c8));
        }
    }
}

// 256-bin suffix scan via wave shfl + 4-wave LDS combine.
__device__ __forceinline__ unsigned suffix_scan_256(unsigned h, int t, unsigned* wtot, unsigned* tot_out) {
    const int lane = t & 63;
    const int w = t >> 6;
    unsigned s = h;
#pragma unroll
    for (int off = 1; off < 64; off <<= 1) {
        unsigned o = __shfl_down(s, off);
        if (lane + off < 64) s += o;
    }
    if (lane == 0) wtot[w] = s;
    __syncthreads();
    unsigned suf = s;
    unsigned tot = 0;
#pragma unroll
    for (int w2 = 0; w2 < 4; ++w2) {
        tot += wtot[w2];
        if (w2 > w) suf += wtot[w2];
    }
    *tot_out = tot;
    return suf;
}

// ---------------- per-row: cutoff/compaction + sequential exact recompute + scatter + decode ----------------
__global__ __launch_bounds__(256) void k_topk2(
    float* __restrict__ sparse,        // [BATCH][D_SAE]: in f16 approx (first half), out final sparse_acts
    const float* __restrict__ x,       // original fp32 [BATCH][D_IN]
    const f16* __restrict__ WhiT, const f16* __restrict__ WloT,
    const float* __restrict__ b_enc,
    const f16* __restrict__ Wdh,       // f16 W_dec [D_SAE][D_IN]
    const float* __restrict__ b_dec,
    float* __restrict__ recon)         // [BATCH][D_IN]
{
    const int row = blockIdx.x;
    const int t = threadIdx.x;
    const int lane = t & 63;
    float* rp = sparse + (size_t)row * D_SAE;
    const f16* ap = (const f16*)rp;

    // ---- load f16 approx row, 48 per thread, coalesced 16B, nontemporal ----
    v8h av[6];
#pragma unroll
    for (int j = 0; j < 6; ++j)
        av[j] = __builtin_nontemporal_load((const v8h*)(ap + ((size_t)j * 256 + t) * 8));

    __shared__ unsigned hist[256];
    __shared__ unsigned wtot[4];
    __shared__ float sh_cutoff;
    __shared__ int sh_ncand;
    __shared__ int   cand_i[CAND_MAX];
    __shared__ float cand_v[CAND_MAX];
    __shared__ float kept_v[K_TOP];
    __shared__ int   kept_i[K_TOP];
    __shared__ float xr[D_IN];

    const float margin = 0.05f;

    hist[t] = 0;
    if (t == 0) sh_ncand = 0;
    // overlap: exact x row (fp32, centered) into LDS for the recompute phase
    for (int k = t; k < D_IN; k += 256)
        xr[k] = x[(size_t)row * D_IN + k] - b_dec[k];
    __syncthreads();

    // ---- level 0: histogram over [2.0, 10.0), 1/32 bins. Top-64/12288 cutoff sits
    // near 3.6 for this problem's statistics; only ~8% of elements take the atomic.
    // Pathological rows fall back to the proven [0.25,8.25) / (0,0.25) ladder. ----
#pragma unroll
    for (int j = 0; j < 6; ++j)
#pragma unroll
        for (int u = 0; u < 8; ++u) {
            float x0 = (float)av[j][u];
            if (x0 >= 2.0f) {
                int b = (int)((x0 - 2.0f) * 32.0f); if (b > 255) b = 255;
                atomicAdd(&hist[b], 1u);
            }
        }
    __syncthreads();
    unsigned h0 = hist[t];
    unsigned tot0;
    unsigned suf0 = suffix_scan_256(h0, t, wtot, &tot0);
    if (tot0 >= K_TOP) {
        if (suf0 >= K_TOP && suf0 - h0 < K_TOP)
            sh_cutoff = fmaxf(2.0f + (float)t * (1.0f / 32.0f) - margin, 1e-30f);
    }
    __syncthreads();
    if (tot0 < K_TOP) {
        // ---- level 1: [0.25, 8.25), 1/32 bins (original proven range) ----
        hist[t] = 0;
        __syncthreads();
#pragma unroll
        for (int j = 0; j < 6; ++j)
#pragma unroll
            for (int u = 0; u < 8; ++u) {
                float x0 = (float)av[j][u];
                if (x0 >= 0.25f) {
                    int b = (int)(x0 * 32.0f); if (b > 255) b = 255;
                    atomicAdd(&hist[b], 1u);
                }
            }
        __syncthreads();
        unsigned h1 = hist[t];
        unsigned tot1;
        unsigned suf1 = suffix_scan_256(h1, t, wtot, &tot1);
        if (tot1 >= K_TOP) {
            if (suf1 >= K_TOP && suf1 - h1 < K_TOP)
                sh_cutoff = fmaxf((float)t * (1.0f / 32.0f) - margin, 1e-30f);
        }
        __syncthreads();
        if (tot1 < K_TOP) {
            // ---- level 2: refine (0, 0.25) ----
            hist[t] = 0;
            __syncthreads();
#pragma unroll
            for (int j = 0; j < 6; ++j)
#pragma unroll
                for (int u = 0; u < 8; ++u) {
                    float x0 = (float)av[j][u];
                    if (x0 > 0.0f && x0 < 0.25f) {
                        int b = (int)(x0 * 1024.0f); if (b > 255) b = 255;
                        atomicAdd(&hist[b], 1u);
                    }
                }
            __syncthreads();
            unsigned h2 = hist[t];
            unsigned tot2;
            unsigned suf2 = suffix_scan_256(h2, t, wtot, &tot2);
            unsigned need = K_TOP - tot1;
            if (tot2 >= need) {
                if (suf2 >= need && suf2 - h2 < need)
                    sh_cutoff = fmaxf((float)t * (1.0f / 1024.0f) - margin, 1e-30f);
            } else {
                if (t == 0) sh_cutoff = 1e-30f;  // fewer than K positives: keep all positives
            }
        }
    }
    __syncthreads();
    const float cutoff = sh_cutoff;

    // ---- collect candidate indices: ballot + prefix-popcount ----
#pragma unroll
    for (int j = 0; j < 6; ++j)
#pragma unroll
        for (int u = 0; u < 8; ++u) {
            float x0 = (float)av[j][u];
            bool pass = (x0 >= cutoff);
            unsigned long long m = __ballot(pass);
            if (m != 0ull) {
                int leader = (int)__builtin_ctzll(m);
                int cnt = (int)__builtin_popcountll(m);
                int base0 = 0;
                if (lane == leader) base0 = atomicAdd(&sh_ncand, cnt);
                base0 = __shfl(base0, leader);
                if (pass) {
                    int pos = base0 + (int)__builtin_popcountll(m & ((1ull << lane) - 1ull));
                    if (pos < CAND_MAX) { cand_i[pos] = (j * 256 + t) * 8 + u; cand_v[pos] = x0; }
                }
            }
        }
    __syncthreads();
    int ncand = sh_ncand; if (ncand > CAND_MAX) ncand = CAND_MAX;

    // ---- exact recompute: SEQUENTIAL k per thread — rounding correlated with
    //      the np reference; DO NOT parallelize or reorder this sum ----
    for (int c = t; c < ncand; c += 256) {
        const f16* wh = WhiT + (size_t)cand_i[c] * D_IN;
        const f16* wl = WloT + (size_t)cand_i[c] * D_IN;
        float acc = 0.f;
        for (int k = 0; k < D_IN; k += 8) {
            v8h hv = *(const v8h*)(wh + k);
            v8h lv = *(const v8h*)(wl + k);
#pragma unroll
            for (int u = 0; u < 8; ++u)
                acc += xr[k + u] * ((float)hv[u] + (float)lv[u]);
        }
        acc += b_enc[cand_i[c]];
        cand_v[c] = acc > 0.f ? acc : 0.f;
    }
    __syncthreads();

    // ---- exact ranking (value desc, index asc), rank-indexed kept store ----
    for (int c = t; c < ncand; c += 256) {
        float vc = cand_v[c]; int ic = cand_i[c];
        int r = 0;
        for (int m = 0; m < ncand; ++m) {
            float vm = cand_v[m];
            r += (vm > vc || (vm == vc && cand_i[m] < ic)) ? 1 : 0;
        }
        if (r < K_TOP) { kept_v[r] = vc; kept_i[r] = ic; }
    }
    __syncthreads();
    int nk = ncand < K_TOP ? ncand : K_TOP;

    // ---- write sparse row: nontemporal zero-fill then scatter exact values ----
#pragma unroll
    for (int j = 0; j < 12; ++j) {
        v4f z = {0.f, 0.f, 0.f, 0.f};
        __builtin_nontemporal_store(z, (v4f*)(rp + ((size_t)j * 256 + t) * 4));
    }
    __syncthreads();
    if (t < nk) rp[kept_i[t]] = kept_v[t];

    // ---- sparse decode (f16 W_dec): recon = sum kept_v * Wdh[kept_i,:] + b_dec ----
    float r0 = b_dec[t], r1 = b_dec[t + 256], r2 = b_dec[t + 512];
#pragma unroll 4
    for (int m = 0; m < nk; ++m) {
        float val = kept_v[m];
        const f16* wr = Wdh + (size_t)kept_i[m] * D_IN;
        r0 += val * (float)wr[t];
        r1 += val * (float)wr[t + 256];
        r2 += val * (float)wr[t + 512];
    }
    float* rc = recon + (size_t)row * D_IN;
    __builtin_nontemporal_store(r0, rc + t);
    __builtin_nontemporal_store(r1, rc + t + 256);
    __builtin_nontemporal_store(r2, rc + t + 512);
}

extern "C" void kernel_launch(void* const* d_in, const int* in_sizes, int n_in,
                              void* d_out, int out_size, void* d_ws, size_t ws_size,
                              hipStream_t stream) {
    const float* x     = (const float*)d_in[0];
    const float* W_enc = (const float*)d_in[1];
    const float* b_enc = (const float*)d_in[2];
    const float* W_dec = (const float*)d_in[3];
    const float* b_dec = (const float*)d_in[4];
    float* out    = (float*)d_out;
    float* recon  = out;                             // [BATCH][D_IN]
    float* sparse = out + (size_t)BATCH * D_IN;      // [BATCH][D_SAE]

    const size_t xplane = (size_t)BATCH * D_IN;      // 6291456
    const size_t wplane = (size_t)D_SAE * D_IN;      // 9437184
    // workspace layout identical to the last PASSING rounds (69.2 MB)
    f16* xhi    = (f16*)d_ws;                        // 12.6 MB
    f16* whiT   = xhi + xplane;                      // 18.9 MB
    f16* wloT   = whiT + wplane;                     // 18.9 MB
    f16* wdh    = wloT + wplane;                     // 18.9 MB

    k_convert_x<<<xplane / 1024, 256, 0, stream>>>(x, b_dec, xhi);
    k_convert_wt<<<dim3(D_SAE / 32, D_IN / 32), 256, 0, stream>>>(W_enc, whiT, wloT);
    k_convert_wd<<<wplane / 1024, 256, 0, stream>>>(W_dec, wdh);
    k_gemm_f16<<<dim3(D_SAE / 128, BATCH / 128), 256, 0, stream>>>(xhi, whiT, b_enc, (f16*)sparse);
    k_topk2<<<BATCH, 256, 0, stream>>>(sparse, x, whiT, wloT, b_enc, wdh, b_dec, recon);
}

// Round 7
// 1196.336 us; speedup vs baseline: 1.1382x; 1.0003x over previous
//
#include <hip/hip_runtime.h>
#include <hip/hip_fp16.h>
#include <stdint.h>

#define D_IN   768
#define D_SAE  12288
#define BATCH  8192
#define K_TOP  64
#define CAND_MAX 256

typedef _Float16 f16;
typedef _Float16 v8h __attribute__((ext_vector_type(8)));
typedef float v4f __attribute__((ext_vector_type(4)));

// async global->LDS, 16B/lane, wave-uniform LDS base (lane writes base + lane*16B)
__device__ inline void async16(const void* g, void* l) {
    __builtin_amdgcn_global_load_lds(
        (const __attribute__((address_space(1))) unsigned int*)g,
        (__attribute__((address_space(3))) unsigned int*)l, 16, 0, 0);
}

// ---------------- convert x: (x - b_dec) -> f16 hi plane [BATCH][D_IN] ----------------
__global__ __launch_bounds__(256) void k_convert_x(
    const float* __restrict__ x, const float* __restrict__ b_dec,
    f16* __restrict__ xhi)
{
    int i4 = (blockIdx.x * 256 + threadIdx.x) * 4;
    float4 v = *(const float4*)(x + i4);
    int col = i4 % D_IN;
    float vv[4] = { v.x - b_dec[col], v.y - b_dec[col + 1],
                    v.z - b_dec[col + 2], v.w - b_dec[col + 3] };
    union { short4 s; f16 h[4]; } H;
#pragma unroll
    for (int u = 0; u < 4; ++u) H.h[u] = (f16)vv[u];
    *(short4*)(xhi + i4) = H.s;
}

// ---------------- convert+transpose W_enc [D_IN][D_SAE] -> hi/lo planes [D_SAE][D_IN] ----------------
__global__ __launch_bounds__(256) void k_convert_wt(
    const float* __restrict__ W, f16* __restrict__ whiT, f16* __restrict__ wloT)
{
    __shared__ float tile[32][33];
    const int n0 = blockIdx.x * 32;
    const int k0 = blockIdx.y * 32;
    const int c = threadIdx.x & 31;
    const int rr = threadIdx.x >> 5;   // 0..7
#pragma unroll
    for (int s = 0; s < 4; ++s) {
        int r = s * 8 + rr;
        tile[r][c] = W[(size_t)(k0 + r) * D_SAE + n0 + c];
    }
    __syncthreads();
#pragma unroll
    for (int s = 0; s < 4; ++s) {
        int r2 = s * 8 + rr;                 // n within tile
        float v = tile[c][r2];               // W[k0+c][n0+r2]
        f16 hi = (f16)v;
        f16 lo = (f16)(v - (float)hi);
        whiT[(size_t)(n0 + r2) * D_IN + k0 + c] = hi;
        wloT[(size_t)(n0 + r2) * D_IN + k0 + c] = lo;
    }
}

// ---------------- convert W_dec [D_SAE][D_IN] fp32 -> f16 (decode is tolerant:
// per-term err <= val*|w|*2^-12, RMS over 64 terms ~2e-4 on recon) ----------------
__global__ __launch_bounds__(256) void k_convert_wd(
    const float* __restrict__ W, f16* __restrict__ Wh)
{
    int i4 = (blockIdx.x * 256 + threadIdx.x) * 4;
    float4 v = *(const float4*)(W + i4);
    union { short4 s; f16 h[4]; } H;
    H.h[0] = (f16)v.x; H.h[1] = (f16)v.y; H.h[2] = (f16)v.z; H.h[3] = (f16)v.w;
    *(short4*)(Wh + i4) = H.s;
}

// ---------------- approximate encode GEMM (f16 MFMA, 128x128 tile, BK=64) ----------------
// Round-6 passing structure + XCD-aware 2-D tile swizzle (T1, chiplet heuristic):
// each XCD (lid%8) owns a contiguous 12-wide B column-band (12 x 196 KB = 2.4 MB,
// fits its 4 MB private L2) and sweeps M bx-fastest within the band (A row-band
// shared by 12 consecutive blocks). Cuts operand re-fetch from L3 ~20x
// (2.4 GB -> ~120 MB). Bijective: 6144 blocks = 8 XCDs x 12 bx x 64 by.
__global__ __launch_bounds__(256) void k_gemm_f16(
    const f16* __restrict__ A,    // Xhi [BATCH][D_IN]
    const f16* __restrict__ Bt,   // WhiT [D_SAE][D_IN]
    const float* __restrict__ b_enc,
    f16* __restrict__ outap)      // rows of 2*D_SAE f16 (= D_SAE fp32): approx in first half
{
    __shared__ union {
        struct { f16 A[2][128 * 32]; f16 B[2][128 * 32]; } ab;   // 32 KB
        f16 C[128 * 136];                                        // 34 KB
    } sm;
    const int tid  = threadIdx.x;
    const int wave = tid >> 6;
    const int lane = tid & 63;

    // ---- XCD swizzle: lid -> (sbx, sby) ----
    const int lid = blockIdx.y * 96 + blockIdx.x;   // dispatch-linear (x fastest)
    const int xcd = lid & 7;
    const int idx = lid >> 3;                       // 0..767 within XCD
    const int sbx = xcd * 12 + (idx % 12);          // 0..95  (column band per XCD)
    const int sby = idx / 12;                       // 0..63  (bx-fastest within band)
    const int bn = sbx * 128;
    const int bm = sby * 128;

    const int r16  = lane >> 2;       // 0..15 staging row
    const int kc8  = (lane & 3) * 8;  // f16 k-offset within 32
    const int mrow = lane & 15;
    const int quad = lane >> 4;
    const int wm = (wave & 1) * 64;
    const int wn = (wave >> 1) * 64;

    v4f acc[4][4] = {};

    const f16* gA = A  + (size_t)(bm + wave * 32 + r16) * D_IN + kc8;
    const f16* gB = Bt + (size_t)(bn + wave * 32 + r16) * D_IN + kc8;
    f16* lA0  = &sm.ab.A[0][(wave * 32) * 32];
    f16* lA0b = &sm.ab.A[0][(wave * 32 + 16) * 32];
    f16* lB0  = &sm.ab.B[0][(wave * 32) * 32];
    f16* lB0b = &sm.ab.B[0][(wave * 32 + 16) * 32];
    f16* lA1  = &sm.ab.A[1][(wave * 32) * 32];
    f16* lA1b = &sm.ab.A[1][(wave * 32 + 16) * 32];
    f16* lB1  = &sm.ab.B[1][(wave * 32) * 32];
    f16* lB1b = &sm.ab.B[1][(wave * 32 + 16) * 32];

    for (int k0 = 0; k0 < D_IN; k0 += 64) {
        __syncthreads();
        async16(gA + k0,               lA0);
        async16(gA + k0 + 16 * D_IN,   lA0b);
        async16(gB + k0,               lB0);
        async16(gB + k0 + 16 * D_IN,   lB0b);
        async16(gA + k0 + 32,              lA1);
        async16(gA + k0 + 32 + 16 * D_IN,  lA1b);
        async16(gB + k0 + 32,              lB1);
        async16(gB + k0 + 32 + 16 * D_IN,  lB1b);
        __syncthreads();

#pragma unroll
        for (int s = 0; s < 2; ++s) {
            v8h af[4], bf[4];
#pragma unroll
            for (int i = 0; i < 4; ++i)
                af[i] = *(const v8h*)&sm.ab.A[s][(wm + i * 16 + mrow) * 32 + quad * 8];
#pragma unroll
            for (int j = 0; j < 4; ++j)
                bf[j] = *(const v8h*)&sm.ab.B[s][(wn + j * 16 + mrow) * 32 + quad * 8];
#pragma unroll
            for (int i = 0; i < 4; ++i)
#pragma unroll
                for (int j = 0; j < 4; ++j)
                    acc[i][j] = __builtin_amdgcn_mfma_f32_16x16x32_f16(af[i], bf[j], acc[i][j], 0, 0, 0);
        }
    }

    // ---- epilogue: C tile -> LDS (values identical: +bias, relu, f16 round) ----
    __syncthreads();   // all waves done reading A/B staging LDS
#pragma unroll
    for (int i = 0; i < 4; ++i)
#pragma unroll
        for (int j = 0; j < 4; ++j)
#pragma unroll
            for (int r = 0; r < 4; ++r) {
                int lrow = wm + i * 16 + quad * 4 + r;
                int lcol = wn + j * 16 + mrow;
                float val = acc[i][j][r] + b_enc[bn + lcol];
                sm.C[lrow * 136 + lcol] = (f16)(val > 0.f ? val : 0.f);
            }
    __syncthreads();
    // ---- coalesced store: 8 rows/thread, 16 B each; wave = 4x 256 B contiguous segments ----
    {
        const int r0 = tid >> 4;          // 0..15
        const int c8 = (tid & 15) * 8;    // 0..120
#pragma unroll
        for (int q = 0; q < 8; ++q) {
            int lrow = r0 + q * 16;
            v8h v = *(const v8h*)&sm.C[lrow * 136 + c8];
            __builtin_nontemporal_store(v,
                (v8h*)(outap + (size_t)(bm + lrow) * (2 * D_SAE) + bn + c8));
        }
    }
}

// 256-bin suffix scan via wave shfl + 4-wave LDS combine.
__device__ __forceinline__ unsigned suffix_scan_256(unsigned h, int t, unsigned* wtot, unsigned* tot_out) {
    const int lane = t & 63;
    const int w = t >> 6;
    unsigned s = h;
#pragma unroll
    for (int off = 1; off < 64; off <<= 1) {
        unsigned o = __shfl_down(s, off);
        if (lane + off < 64) s += o;
    }
    if (lane == 0) wtot[w] = s;
    __syncthreads();
    unsigned suf = s;
    unsigned tot = 0;
#pragma unroll
    for (int w2 = 0; w2 < 4; ++w2) {
        tot += wtot[w2];
        if (w2 > w) suf += wtot[w2];
    }
    *tot_out = tot;
    return suf;
}

// ---------------- per-row: cutoff/compaction + sequential exact recompute + scatter + decode ----------------
__global__ __launch_bounds__(256) void k_topk2(
    float* __restrict__ sparse,        // [BATCH][D_SAE]: in f16 approx (first half), out final sparse_acts
    const float* __restrict__ x,       // original fp32 [BATCH][D_IN]
    const f16* __restrict__ WhiT, const f16* __restrict__ WloT,
    const float* __restrict__ b_enc,
    const f16* __restrict__ Wdh,       // f16 W_dec [D_SAE][D_IN]
    const float* __restrict__ b_dec,
    float* __restrict__ recon)         // [BATCH][D_IN]
{
    const int row = blockIdx.x;
    const int t = threadIdx.x;
    const int lane = t & 63;
    float* rp = sparse + (size_t)row * D_SAE;
    const f16* ap = (const f16*)rp;

    // ---- load f16 approx row, 48 per thread, coalesced 16B, nontemporal ----
    v8h av[6];
#pragma unroll
    for (int j = 0; j < 6; ++j)
        av[j] = __builtin_nontemporal_load((const v8h*)(ap + ((size_t)j * 256 + t) * 8));

    __shared__ unsigned hist[256];
    __shared__ unsigned wtot[4];
    __shared__ float sh_cutoff;
    __shared__ int sh_ncand;
    __shared__ int   cand_i[CAND_MAX];
    __shared__ float cand_v[CAND_MAX];
    __shared__ float kept_v[K_TOP];
    __shared__ int   kept_i[K_TOP];
    __shared__ float xr[D_IN];

    const float margin = 0.05f;

    hist[t] = 0;
    if (t == 0) sh_ncand = 0;
    // overlap: exact x row (fp32, centered) into LDS for the recompute phase
    for (int k = t; k < D_IN; k += 256)
        xr[k] = x[(size_t)row * D_IN + k] - b_dec[k];
    __syncthreads();

    // ---- level 0: histogram over [2.0, 10.0), 1/32 bins. Top-64/12288 cutoff sits
    // near 3.6 for this problem's statistics; only ~8% of elements take the atomic.
    // Pathological rows fall back to the proven [0.25,8.25) / (0,0.25) ladder. ----
#pragma unroll
    for (int j = 0; j < 6; ++j)
#pragma unroll
        for (int u = 0; u < 8; ++u) {
            float x0 = (float)av[j][u];
            if (x0 >= 2.0f) {
                int b = (int)((x0 - 2.0f) * 32.0f); if (b > 255) b = 255;
                atomicAdd(&hist[b], 1u);
            }
        }
    __syncthreads();
    unsigned h0 = hist[t];
    unsigned tot0;
    unsigned suf0 = suffix_scan_256(h0, t, wtot, &tot0);
    if (tot0 >= K_TOP) {
        if (suf0 >= K_TOP && suf0 - h0 < K_TOP)
            sh_cutoff = fmaxf(2.0f + (float)t * (1.0f / 32.0f) - margin, 1e-30f);
    }
    __syncthreads();
    if (tot0 < K_TOP) {
        // ---- level 1: [0.25, 8.25), 1/32 bins (original proven range) ----
        hist[t] = 0;
        __syncthreads();
#pragma unroll
        for (int j = 0; j < 6; ++j)
#pragma unroll
            for (int u = 0; u < 8; ++u) {
                float x0 = (float)av[j][u];
                if (x0 >= 0.25f) {
                    int b = (int)(x0 * 32.0f); if (b > 255) b = 255;
                    atomicAdd(&hist[b], 1u);
                }
            }
        __syncthreads();
        unsigned h1 = hist[t];
        unsigned tot1;
        unsigned suf1 = suffix_scan_256(h1, t, wtot, &tot1);
        if (tot1 >= K_TOP) {
            if (suf1 >= K_TOP && suf1 - h1 < K_TOP)
                sh_cutoff = fmaxf((float)t * (1.0f / 32.0f) - margin, 1e-30f);
        }
        __syncthreads();
        if (tot1 < K_TOP) {
            // ---- level 2: refine (0, 0.25) ----
            hist[t] = 0;
            __syncthreads();
#pragma unroll
            for (int j = 0; j < 6; ++j)
#pragma unroll
                for (int u = 0; u < 8; ++u) {
                    float x0 = (float)av[j][u];
                    if (x0 > 0.0f && x0 < 0.25f) {
                        int b = (int)(x0 * 1024.0f); if (b > 255) b = 255;
                        atomicAdd(&hist[b], 1u);
                    }
                }
            __syncthreads();
            unsigned h2 = hist[t];
            unsigned tot2;
            unsigned suf2 = suffix_scan_256(h2, t, wtot, &tot2);
            unsigned need = K_TOP - tot1;
            if (tot2 >= need) {
                if (suf2 >= need && suf2 - h2 < need)
                    sh_cutoff = fmaxf((float)t * (1.0f / 1024.0f) - margin, 1e-30f);
            } else {
                if (t == 0) sh_cutoff = 1e-30f;  // fewer than K positives: keep all positives
            }
        }
    }
    __syncthreads();
    const float cutoff = sh_cutoff;

    // ---- collect candidate indices: ballot + prefix-popcount ----
#pragma unroll
    for (int j = 0; j < 6; ++j)
#pragma unroll
        for (int u = 0; u < 8; ++u) {
            float x0 = (float)av[j][u];
            bool pass = (x0 >= cutoff);
            unsigned long long m = __ballot(pass);
            if (m != 0ull) {
                int leader = (int)__builtin_ctzll(m);
                int cnt = (int)__builtin_popcountll(m);
                int base0 = 0;
                if (lane == leader) base0 = atomicAdd(&sh_ncand, cnt);
                base0 = __shfl(base0, leader);
                if (pass) {
                    int pos = base0 + (int)__builtin_popcountll(m & ((1ull << lane) - 1ull));
                    if (pos < CAND_MAX) { cand_i[pos] = (j * 256 + t) * 8 + u; cand_v[pos] = x0; }
                }
            }
        }
    __syncthreads();
    int ncand = sh_ncand; if (ncand > CAND_MAX) ncand = CAND_MAX;

    // ---- exact recompute: SEQUENTIAL k per thread — rounding correlated with
    //      the np reference; DO NOT parallelize or reorder this sum ----
    for (int c = t; c < ncand; c += 256) {
        const f16* wh = WhiT + (size_t)cand_i[c] * D_IN;
        const f16* wl = WloT + (size_t)cand_i[c] * D_IN;
        float acc = 0.f;
        for (int k = 0; k < D_IN; k += 8) {
            v8h hv = *(const v8h*)(wh + k);
            v8h lv = *(const v8h*)(wl + k);
#pragma unroll
            for (int u = 0; u < 8; ++u)
                acc += xr[k + u] * ((float)hv[u] + (float)lv[u]);
        }
        acc += b_enc[cand_i[c]];
        cand_v[c] = acc > 0.f ? acc : 0.f;
    }
    __syncthreads();

    // ---- exact ranking (value desc, index asc), rank-indexed kept store ----
    for (int c = t; c < ncand; c += 256) {
        float vc = cand_v[c]; int ic = cand_i[c];
        int r = 0;
        for (int m = 0; m < ncand; ++m) {
            float vm = cand_v[m];
            r += (vm > vc || (vm == vc && cand_i[m] < ic)) ? 1 : 0;
        }
        if (r < K_TOP) { kept_v[r] = vc; kept_i[r] = ic; }
    }
    __syncthreads();
    int nk = ncand < K_TOP ? ncand : K_TOP;

    // ---- write sparse row: nontemporal zero-fill then scatter exact values ----
#pragma unroll
    for (int j = 0; j < 12; ++j) {
        v4f z = {0.f, 0.f, 0.f, 0.f};
        __builtin_nontemporal_store(z, (v4f*)(rp + ((size_t)j * 256 + t) * 4));
    }
    __syncthreads();
    if (t < nk) rp[kept_i[t]] = kept_v[t];

    // ---- sparse decode (f16 W_dec): recon = sum kept_v * Wdh[kept_i,:] + b_dec ----
    float r0 = b_dec[t], r1 = b_dec[t + 256], r2 = b_dec[t + 512];
#pragma unroll 4
    for (int m = 0; m < nk; ++m) {
        float val = kept_v[m];
        const f16* wr = Wdh + (size_t)kept_i[m] * D_IN;
        r0 += val * (float)wr[t];
        r1 += val * (float)wr[t + 256];
        r2 += val * (float)wr[t + 512];
    }
    float* rc = recon + (size_t)row * D_IN;
    __builtin_nontemporal_store(r0, rc + t);
    __builtin_nontemporal_store(r1, rc + t + 256);
    __builtin_nontemporal_store(r2, rc + t + 512);
}

extern "C" void kernel_launch(void* const* d_in, const int* in_sizes, int n_in,
                              void* d_out, int out_size, void* d_ws, size_t ws_size,
                              hipStream_t stream) {
    const float* x     = (const float*)d_in[0];
    const float* W_enc = (const float*)d_in[1];
    const float* b_enc = (const float*)d_in[2];
    const float* W_dec = (const float*)d_in[3];
    const float* b_dec = (const float*)d_in[4];
    float* out    = (float*)d_out;
    float* recon  = out;                             // [BATCH][D_IN]
    float* sparse = out + (size_t)BATCH * D_IN;      // [BATCH][D_SAE]

    const size_t xplane = (size_t)BATCH * D_IN;      // 6291456
    const size_t wplane = (size_t)D_SAE * D_IN;      // 9437184
    // workspace layout identical to the last PASSING rounds (69.2 MB)
    f16* xhi    = (f16*)d_ws;                        // 12.6 MB
    f16* whiT   = xhi + xplane;                      // 18.9 MB
    f16* wloT   = whiT + wplane;                     // 18.9 MB
    f16* wdh    = wloT + wplane;                     // 18.9 MB

    k_convert_x<<<xplane / 1024, 256, 0, stream>>>(x, b_dec, xhi);
    k_convert_wt<<<dim3(D_SAE / 32, D_IN / 32), 256, 0, stream>>>(W_enc, whiT, wloT);
    k_convert_wd<<<wplane / 1024, 256, 0, stream>>>(W_dec, wdh);
    k_gemm_f16<<<dim3(96, 64), 256, 0, stream>>>(xhi, whiT, b_enc, (f16*)sparse);
    k_topk2<<<BATCH, 256, 0, stream>>>(sparse, x, whiT, wloT, b_enc, wdh, b_dec, recon);
}

// Round 9
// 1128.997 us; speedup vs baseline: 1.2061x; 1.0596x over previous
//
#include <hip/hip_runtime.h>
#include <hip/hip_fp16.h>
#include <stdint.h>

#define D_IN   768
#define D_SAE  12288
#define BATCH  8192
#define K_TOP  64
#define CAND_MAX 256

// HARD CONSTRAINT (learned rounds 3/4/8): workspace must stay within the proven
// 69.3 MB layout {xhi, whiT, wloT, wdh}. +32 KB crashed the container (r4);
// +18.8 MB silently corrupted memory (r8, absmax 0.59).

typedef _Float16 f16;
typedef _Float16 v8h __attribute__((ext_vector_type(8)));
typedef float v4f __attribute__((ext_vector_type(4)));

// async global->LDS, 16B/lane, wave-uniform LDS base (lane writes base + lane*16B)
__device__ inline void async16(const void* g, void* l) {
    __builtin_amdgcn_global_load_lds(
        (const __attribute__((address_space(1))) unsigned int*)g,
        (__attribute__((address_space(3))) unsigned int*)l, 16, 0, 0);
}

// ---------------- convert x: (x - b_dec) -> f16 hi plane [BATCH][D_IN] ----------------
__global__ __launch_bounds__(256) void k_convert_x(
    const float* __restrict__ x, const float* __restrict__ b_dec,
    f16* __restrict__ xhi)
{
    int i4 = (blockIdx.x * 256 + threadIdx.x) * 4;
    float4 v = *(const float4*)(x + i4);
    int col = i4 % D_IN;
    float vv[4] = { v.x - b_dec[col], v.y - b_dec[col + 1],
                    v.z - b_dec[col + 2], v.w - b_dec[col + 3] };
    union { short4 s; f16 h[4]; } H;
#pragma unroll
    for (int u = 0; u < 4; ++u) H.h[u] = (f16)vv[u];
    *(short4*)(xhi + i4) = H.s;
}

// ---------------- convert+transpose W_enc [D_IN][D_SAE] -> hi/lo planes [D_SAE][D_IN] ----------------
__global__ __launch_bounds__(256) void k_convert_wt(
    const float* __restrict__ W, f16* __restrict__ whiT, f16* __restrict__ wloT)
{
    __shared__ float tile[32][33];
    const int n0 = blockIdx.x * 32;
    const int k0 = blockIdx.y * 32;
    const int c = threadIdx.x & 31;
    const int rr = threadIdx.x >> 5;   // 0..7
#pragma unroll
    for (int s = 0; s < 4; ++s) {
        int r = s * 8 + rr;
        tile[r][c] = W[(size_t)(k0 + r) * D_SAE + n0 + c];
    }
    __syncthreads();
#pragma unroll
    for (int s = 0; s < 4; ++s) {
        int r2 = s * 8 + rr;                 // n within tile
        float v = tile[c][r2];               // W[k0+c][n0+r2]
        f16 hi = (f16)v;
        f16 lo = (f16)(v - (float)hi);
        whiT[(size_t)(n0 + r2) * D_IN + k0 + c] = hi;
        wloT[(size_t)(n0 + r2) * D_IN + k0 + c] = lo;
    }
}

// ---------------- convert W_dec [D_SAE][D_IN] fp32 -> f16 (decode is tolerant:
// per-term err <= val*|w|*2^-12, RMS over 64 terms ~2e-4 on recon) ----------------
__global__ __launch_bounds__(256) void k_convert_wd(
    const float* __restrict__ W, f16* __restrict__ Wh)
{
    int i4 = (blockIdx.x * 256 + threadIdx.x) * 4;
    float4 v = *(const float4*)(W + i4);
    union { short4 s; f16 h[4]; } H;
    H.h[0] = (f16)v.x; H.h[1] = (f16)v.y; H.h[2] = (f16)v.z; H.h[3] = (f16)v.w;
    *(short4*)(Wh + i4) = H.s;
}

// ---------------- approximate encode GEMM (f16 MFMA, 128x128 tile, BK=64) ----------------
// Round-7 passing structure (XCD swizzle kept; LDS-coalesced nt C-store).
__global__ __launch_bounds__(256) void k_gemm_f16(
    const f16* __restrict__ A,    // Xhi [BATCH][D_IN]
    const f16* __restrict__ Bt,   // WhiT [D_SAE][D_IN]
    const float* __restrict__ b_enc,
    f16* __restrict__ outap)      // rows of 2*D_SAE f16 (= D_SAE fp32): approx in first half
{
    __shared__ union {
        struct { f16 A[2][128 * 32]; f16 B[2][128 * 32]; } ab;   // 32 KB
        f16 C[128 * 136];                                        // 34 KB
    } sm;
    const int tid  = threadIdx.x;
    const int wave = tid >> 6;
    const int lane = tid & 63;

    const int lid = blockIdx.y * 96 + blockIdx.x;
    const int xcd = lid & 7;
    const int idx = lid >> 3;
    const int sbx = xcd * 12 + (idx % 12);
    const int sby = idx / 12;
    const int bn = sbx * 128;
    const int bm = sby * 128;

    const int r16  = lane >> 2;
    const int kc8  = (lane & 3) * 8;
    const int mrow = lane & 15;
    const int quad = lane >> 4;
    const int wm = (wave & 1) * 64;
    const int wn = (wave >> 1) * 64;

    v4f acc[4][4] = {};

    const f16* gA = A  + (size_t)(bm + wave * 32 + r16) * D_IN + kc8;
    const f16* gB = Bt + (size_t)(bn + wave * 32 + r16) * D_IN + kc8;
    f16* lA0  = &sm.ab.A[0][(wave * 32) * 32];
    f16* lA0b = &sm.ab.A[0][(wave * 32 + 16) * 32];
    f16* lB0  = &sm.ab.B[0][(wave * 32) * 32];
    f16* lB0b = &sm.ab.B[0][(wave * 32 + 16) * 32];
    f16* lA1  = &sm.ab.A[1][(wave * 32) * 32];
    f16* lA1b = &sm.ab.A[1][(wave * 32 + 16) * 32];
    f16* lB1  = &sm.ab.B[1][(wave * 32) * 32];
    f16* lB1b = &sm.ab.B[1][(wave * 32 + 16) * 32];

    for (int k0 = 0; k0 < D_IN; k0 += 64) {
        __syncthreads();
        async16(gA + k0,               lA0);
        async16(gA + k0 + 16 * D_IN,   lA0b);
        async16(gB + k0,               lB0);
        async16(gB + k0 + 16 * D_IN,   lB0b);
        async16(gA + k0 + 32,              lA1);
        async16(gA + k0 + 32 + 16 * D_IN,  lA1b);
        async16(gB + k0 + 32,              lB1);
        async16(gB + k0 + 32 + 16 * D_IN,  lB1b);
        __syncthreads();

#pragma unroll
        for (int s = 0; s < 2; ++s) {
            v8h af[4], bf[4];
#pragma unroll
            for (int i = 0; i < 4; ++i)
                af[i] = *(const v8h*)&sm.ab.A[s][(wm + i * 16 + mrow) * 32 + quad * 8];
#pragma unroll
            for (int j = 0; j < 4; ++j)
                bf[j] = *(const v8h*)&sm.ab.B[s][(wn + j * 16 + mrow) * 32 + quad * 8];
#pragma unroll
            for (int i = 0; i < 4; ++i)
#pragma unroll
                for (int j = 0; j < 4; ++j)
                    acc[i][j] = __builtin_amdgcn_mfma_f32_16x16x32_f16(af[i], bf[j], acc[i][j], 0, 0, 0);
        }
    }

    __syncthreads();
#pragma unroll
    for (int i = 0; i < 4; ++i)
#pragma unroll
        for (int j = 0; j < 4; ++j)
#pragma unroll
            for (int r = 0; r < 4; ++r) {
                int lrow = wm + i * 16 + quad * 4 + r;
                int lcol = wn + j * 16 + mrow;
                float val = acc[i][j][r] + b_enc[bn + lcol];
                sm.C[lrow * 136 + lcol] = (f16)(val > 0.f ? val : 0.f);
            }
    __syncthreads();
    {
        const int r0 = tid >> 4;
        const int c8 = (tid & 15) * 8;
#pragma unroll
        for (int q = 0; q < 8; ++q) {
            int lrow = r0 + q * 16;
            v8h v = *(const v8h*)&sm.C[lrow * 136 + c8];
            __builtin_nontemporal_store(v,
                (v8h*)(outap + (size_t)(bm + lrow) * (2 * D_SAE) + bn + c8));
        }
    }
}

// 256-bin suffix scan via wave shfl + 4-wave LDS combine.
__device__ __forceinline__ unsigned suffix_scan_256(unsigned h, int t, unsigned* wtot, unsigned* tot_out) {
    const int lane = t & 63;
    const int w = t >> 6;
    unsigned s = h;
#pragma unroll
    for (int off = 1; off < 64; off <<= 1) {
        unsigned o = __shfl_down(s, off);
        if (lane + off < 64) s += o;
    }
    if (lane == 0) wtot[w] = s;
    __syncthreads();
    unsigned suf = s;
    unsigned tot = 0;
#pragma unroll
    for (int w2 = 0; w2 < 4; ++w2) {
        tot += wtot[w2];
        if (w2 > w) suf += wtot[w2];
    }
    *tot_out = tot;
    return suf;
}

// ---------------- per-row: cutoff/compaction + staged exact recompute + scatter + decode ----------------
__global__ __launch_bounds__(256) void k_topk2(
    float* __restrict__ sparse,        // [BATCH][D_SAE]: in f16 approx (first half), out final sparse_acts
    const float* __restrict__ x,       // original fp32 [BATCH][D_IN]
    const f16* __restrict__ WhiT, const f16* __restrict__ WloT,
    const float* __restrict__ b_enc,
    const f16* __restrict__ Wdh,       // f16 W_dec [D_SAE][D_IN]
    const float* __restrict__ b_dec,
    float* __restrict__ recon)         // [BATCH][D_IN]
{
    const int row = blockIdx.x;
    const int t = threadIdx.x;
    const int lane = t & 63;
    float* rp = sparse + (size_t)row * D_SAE;
    const f16* ap = (const f16*)rp;

    // ---- load f16 approx row, 48 per thread, coalesced 16B, nontemporal (proven) ----
    v8h av[6];
#pragma unroll
    for (int j = 0; j < 6; ++j)
        av[j] = __builtin_nontemporal_load((const v8h*)(ap + ((size_t)j * 256 + t) * 8));

    __shared__ unsigned hist[256];
    __shared__ unsigned wtot[4];
    __shared__ float sh_cutoff;
    __shared__ int sh_ncand;
    __shared__ int   cand_i[CAND_MAX];
    __shared__ float cand_v[CAND_MAX];
    __shared__ float kept_v[K_TOP];
    __shared__ int   kept_i[K_TOP];
    __shared__ float xr[D_IN];
    __shared__ float wstage[64][67];   // staged cand weights (hi+lo, fp32); stride 67 -> conflict-free

    const float margin = 0.05f;

    hist[t] = 0;
    if (t == 0) sh_ncand = 0;
    // overlap: exact x row (fp32, centered) into LDS for the recompute phase
    for (int k = t; k < D_IN; k += 256)
        xr[k] = x[(size_t)row * D_IN + k] - b_dec[k];
    __syncthreads();

    // ---- level 0: histogram over [2.0, 10.0), 1/32 bins ----
#pragma unroll
    for (int j = 0; j < 6; ++j)
#pragma unroll
        for (int u = 0; u < 8; ++u) {
            float x0 = (float)av[j][u];
            if (x0 >= 2.0f) {
                int b = (int)((x0 - 2.0f) * 32.0f); if (b > 255) b = 255;
                atomicAdd(&hist[b], 1u);
            }
        }
    __syncthreads();
    unsigned h0 = hist[t];
    unsigned tot0;
    unsigned suf0 = suffix_scan_256(h0, t, wtot, &tot0);
    if (tot0 >= K_TOP) {
        if (suf0 >= K_TOP && suf0 - h0 < K_TOP)
            sh_cutoff = fmaxf(2.0f + (float)t * (1.0f / 32.0f) - margin, 1e-30f);
    }
    __syncthreads();
    if (tot0 < K_TOP) {
        // ---- level 1: [0.25, 8.25) ----
        hist[t] = 0;
        __syncthreads();
#pragma unroll
        for (int j = 0; j < 6; ++j)
#pragma unroll
            for (int u = 0; u < 8; ++u) {
                float x0 = (float)av[j][u];
                if (x0 >= 0.25f) {
                    int b = (int)(x0 * 32.0f); if (b > 255) b = 255;
                    atomicAdd(&hist[b], 1u);
                }
            }
        __syncthreads();
        unsigned h1 = hist[t];
        unsigned tot1;
        unsigned suf1 = suffix_scan_256(h1, t, wtot, &tot1);
        if (tot1 >= K_TOP) {
            if (suf1 >= K_TOP && suf1 - h1 < K_TOP)
                sh_cutoff = fmaxf((float)t * (1.0f / 32.0f) - margin, 1e-30f);
        }
        __syncthreads();
        if (tot1 < K_TOP) {
            // ---- level 2: refine (0, 0.25) ----
            hist[t] = 0;
            __syncthreads();
#pragma unroll
            for (int j = 0; j < 6; ++j)
#pragma unroll
                for (int u = 0; u < 8; ++u) {
                    float x0 = (float)av[j][u];
                    if (x0 > 0.0f && x0 < 0.25f) {
                        int b = (int)(x0 * 1024.0f); if (b > 255) b = 255;
                        atomicAdd(&hist[b], 1u);
                    }
                }
            __syncthreads();
            unsigned h2 = hist[t];
            unsigned tot2;
            unsigned suf2 = suffix_scan_256(h2, t, wtot, &tot2);
            unsigned need = K_TOP - tot1;
            if (tot2 >= need) {
                if (suf2 >= need && suf2 - h2 < need)
                    sh_cutoff = fmaxf((float)t * (1.0f / 1024.0f) - margin, 1e-30f);
            } else {
                if (t == 0) sh_cutoff = 1e-30f;
            }
        }
    }
    __syncthreads();
    const float cutoff = sh_cutoff;

    // ---- collect candidate indices: ballot + prefix-popcount ----
#pragma unroll
    for (int j = 0; j < 6; ++j)
#pragma unroll
        for (int u = 0; u < 8; ++u) {
            float x0 = (float)av[j][u];
            bool pass = (x0 >= cutoff);
            unsigned long long m = __ballot(pass);
            if (m != 0ull) {
                int leader = (int)__builtin_ctzll(m);
                int cnt = (int)__builtin_popcountll(m);
                int base0 = 0;
                if (lane == leader) base0 = atomicAdd(&sh_ncand, cnt);
                base0 = __shfl(base0, leader);
                if (pass) {
                    int pos = base0 + (int)__builtin_popcountll(m & ((1ull << lane) - 1ull));
                    if (pos < CAND_MAX) { cand_i[pos] = (j * 256 + t) * 8 + u; cand_v[pos] = x0; }
                }
            }
        }
    __syncthreads();
    int ncand = sh_ncand; if (ncand > CAND_MAX) ncand = CAND_MAX;

    // ---- exact recompute, LDS-staged (round-9):
    //      64-cand chunks; staging loads hi/lo coalesced (8 threads x 16 B per
    //      row-chunk = 128 B contiguous) and stores w = (float)hi + (float)lo —
    //      the EXACT proven expression. Per-candidate dot is SEQUENTIAL ascending-k
    //      (chunk asc, within-chunk asc): op sequence bitwise identical to the
    //      proven per-thread walk. DO NOT parallelize or reorder the sum. ----
    for (int cb = 0; cb < ncand; cb += 64) {
        float acc = 0.f;
        const int c = cb + t;
        const bool act = (t < 64) && (c < ncand);
        for (int kc = 0; kc < D_IN; kc += 64) {
            __syncthreads();                         // prev chunk's readers done
#pragma unroll
            for (int pass = 0; pass < 2; ++pass) {   // 32 rows/pass, 8 threads x 8 wts per row
                int rr = pass * 32 + (t >> 3);
                int e8 = (t & 7) * 8;
                if (cb + rr < ncand) {
                    const f16* wh = WhiT + (size_t)cand_i[cb + rr] * D_IN + kc + e8;
                    const f16* wl = WloT + (size_t)cand_i[cb + rr] * D_IN + kc + e8;
                    v8h hv = *(const v8h*)wh;
                    v8h lv = *(const v8h*)wl;
#pragma unroll
                    for (int u = 0; u < 8; ++u)
                        wstage[rr][e8 + u] = (float)hv[u] + (float)lv[u];
                }
            }
            __syncthreads();
            if (act) {
#pragma unroll
                for (int kk = 0; kk < 64; ++kk)
                    acc += xr[kc + kk] * wstage[t][kk];
            }
        }
        if (act) {
            acc += b_enc[cand_i[c]];
            cand_v[c] = acc > 0.f ? acc : 0.f;
        }
    }
    __syncthreads();

    // ---- exact ranking (value desc, index asc), rank-indexed kept store ----
    for (int c = t; c < ncand; c += 256) {
        float vc = cand_v[c]; int ic = cand_i[c];
        int r = 0;
        for (int m = 0; m < ncand; ++m) {
            float vm = cand_v[m];
            r += (vm > vc || (vm == vc && cand_i[m] < ic)) ? 1 : 0;
        }
        if (r < K_TOP) { kept_v[r] = vc; kept_i[r] = ic; }
    }
    __syncthreads();
    int nk = ncand < K_TOP ? ncand : K_TOP;

    // ---- write sparse row: nontemporal zero-fill then scatter exact values ----
#pragma unroll
    for (int j = 0; j < 12; ++j) {
        v4f z = {0.f, 0.f, 0.f, 0.f};
        __builtin_nontemporal_store(z, (v4f*)(rp + ((size_t)j * 256 + t) * 4));
    }
    __syncthreads();
    if (t < nk) rp[kept_i[t]] = kept_v[t];

    // ---- sparse decode (f16 W_dec): recon = sum kept_v * Wdh[kept_i,:] + b_dec ----
    float r0 = b_dec[t], r1 = b_dec[t + 256], r2 = b_dec[t + 512];
#pragma unroll 4
    for (int m = 0; m < nk; ++m) {
        float val = kept_v[m];
        const f16* wr = Wdh + (size_t)kept_i[m] * D_IN;
        r0 += val * (float)wr[t];
        r1 += val * (float)wr[t + 256];
        r2 += val * (float)wr[t + 512];
    }
    float* rc = recon + (size_t)row * D_IN;
    __builtin_nontemporal_store(r0, rc + t);
    __builtin_nontemporal_store(r1, rc + t + 256);
    __builtin_nontemporal_store(r2, rc + t + 512);
}

extern "C" void kernel_launch(void* const* d_in, const int* in_sizes, int n_in,
                              void* d_out, int out_size, void* d_ws, size_t ws_size,
                              hipStream_t stream) {
    const float* x     = (const float*)d_in[0];
    const float* W_enc = (const float*)d_in[1];
    const float* b_enc = (const float*)d_in[2];
    const float* W_dec = (const float*)d_in[3];
    const float* b_dec = (const float*)d_in[4];
    float* out    = (float*)d_out;
    float* recon  = out;                             // [BATCH][D_IN]
    float* sparse = out + (size_t)BATCH * D_IN;      // [BATCH][D_SAE]

    const size_t xplane = (size_t)BATCH * D_IN;      // 6291456
    const size_t wplane = (size_t)D_SAE * D_IN;      // 9437184
    // workspace layout: PROVEN 69.3 MB — do not exceed (r3/r4/r8 failures)
    f16* xhi    = (f16*)d_ws;                        // 12.6 MB
    f16* whiT   = xhi + xplane;                      // 18.9 MB
    f16* wloT   = whiT + wplane;                     // 18.9 MB
    f16* wdh    = wloT + wplane;                     // 18.9 MB

    k_convert_x<<<xplane / 1024, 256, 0, stream>>>(x, b_dec, xhi);
    k_convert_wt<<<dim3(D_SAE / 32, D_IN / 32), 256, 0, stream>>>(W_enc, whiT, wloT);
    k_convert_wd<<<wplane / 1024, 256, 0, stream>>>(W_dec, wdh);
    k_gemm_f16<<<dim3(96, 64), 256, 0, stream>>>(xhi, whiT, b_enc, (f16*)sparse);
    k_topk2<<<BATCH, 256, 0, stream>>>(sparse, x, whiT, wloT, b_enc, wdh, b_dec, recon);
}